// Round 18
// baseline (211.735 us; speedup 1.0000x reference)
//
#include <hip/hip_runtime.h>
#include <hip/hip_bf16.h>
#include <stdint.h>

typedef short bf8 __attribute__((ext_vector_type(8)));     // 8 x bf16 (4 VGPR)
typedef float f32x4 __attribute__((ext_vector_type(4)));

#define LN_EPS 1e-5f

__device__ __forceinline__ uint16_t f2bf(float f) {
    __hip_bfloat16 h = __float2bfloat16(f);           // RNE
    return __builtin_bit_cast(uint16_t, h);
}
__device__ __forceinline__ float bf2f(uint32_t u) {
    return __uint_as_float(u << 16);
}

__device__ __forceinline__ void gld16(const void* g, void* l) {
    __builtin_amdgcn_global_load_lds(
        (const __attribute__((address_space(1))) uint32_t*)(uintptr_t)g,
        (__attribute__((address_space(3))) uint32_t*)(uint32_t)(uintptr_t)l,
        16, 0, 0);
}

// ---------------- fp32 -> bf16 convert (weights only now) ----------------------
__global__ void cvt_bf16(const float* __restrict__ s0, const float* __restrict__ s1,
                         const float* __restrict__ s2, const float* __restrict__ s3,
                         uint16_t* d0, uint16_t* d1, uint16_t* d2, uint16_t* d3, int n4) {
    const float* ss[4] = {s0, s1, s2, s3};
    uint16_t*    dd[4] = {d0, d1, d2, d3};
    const float* s = ss[blockIdx.z];
    uint16_t*    d = dd[blockIdx.z];
    int i = blockIdx.x * blockDim.x + threadIdx.x;
    int stride = gridDim.x * blockDim.x;
    for (; i < n4; i += stride) {
        float4 f = ((const float4*)s)[i];
        ushort4 u;
        u.x = f2bf(f.x); u.y = f2bf(f.y); u.z = f2bf(f.z); u.w = f2bf(f.w);
        ((ushort4*)d)[i] = u;
    }
}

// ---------------- mask -> per-lane bit words -----------------------------------
// m2[((b*1024+row)*8 + w)*4 + g], bit (cf*4+i) = mask[b][row][w*128+cf*16+g*4+i]
__global__ __launch_bounds__(256) void mask_bits(const int* __restrict__ mask,
                                                 uint32_t* __restrict__ m2) {
    int idx = blockIdx.x * 256 + threadIdx.x;   // 131072 words
    int b = idx >> 15, row = (idx >> 5) & 1023, w = (idx >> 2) & 7, g = idx & 3;
    const int* mrow = mask + ((size_t)b * 1024 + row) * 1024 + w * 128 + g * 4;
    uint32_t bits = 0;
#pragma unroll
    for (int cf = 0; cf < 8; ++cf) {
        int4 mv = *(const int4*)&mrow[cf * 16];
        bits |= (mv.x ? 1u : 0u) << (cf * 4);
        bits |= (mv.y ? 1u : 0u) << (cf * 4 + 1);
        bits |= (mv.z ? 1u : 0u) << (cf * 4 + 2);
        bits |= (mv.w ? 1u : 0u) << (cf * 4 + 3);
    }
    m2[idx] = bits;
}

// ---------------- GEMM: C[r][c] = (sum_d A[r][d]*W[c][d] + bias[c]) * scale ----
// A either bf16 (afp=0, gld16-staged) or fp32 (afp=1, reg-staged + cvt fused).
// mode 0: bf16 head layout; mode 2: bf16 V-transposed; mode 4: bf16 plain.
struct GArgs { const void* A; const uint16_t* W; const float* bias; void* out; int mode; int afp; float scale; };
struct GArgs3 { GArgs g[3]; };

__global__ __launch_bounds__(256) void gemm_bt(GArgs3 args, int Kd) {
    const GArgs ga = args.g[blockIdx.z];
    const uint16_t* __restrict__ Bw = ga.W;
    const float* __restrict__ bias  = ga.bias;
    void* __restrict__ out = ga.out;
    const int mode = ga.mode, afp = ga.afp;
    const float scale = ga.scale;

    __shared__ uint16_t As[2][128][64];
    __shared__ uint16_t Bs[2][128][64];
    const int tid = threadIdx.x;
    const int lane = tid & 63, w = tid >> 6;
    const int wr = w >> 1, wc = w & 1;
    const int tm = blockIdx.y * 128, tn = blockIdx.x * 128;

    f32x4 acc[4][4] = {};

    auto stage = [&](int buf, int kt) {
#pragma unroll
        for (int j = 0; j < 4; ++j) {
            int rr = (w * 4 + j) * 8 + (lane >> 3);
            int cc = (lane & 7) * 8;
            if (afp) {
                const float* Ap = (const float*)ga.A + (size_t)(tm + rr) * Kd + kt * 64 + cc;
                float4 f0 = *(const float4*)Ap;
                float4 f1 = *(const float4*)(Ap + 4);
                ushort4 u0, u1;
                u0.x = f2bf(f0.x); u0.y = f2bf(f0.y); u0.z = f2bf(f0.z); u0.w = f2bf(f0.w);
                u1.x = f2bf(f1.x); u1.y = f2bf(f1.y); u1.z = f2bf(f1.z); u1.w = f2bf(f1.w);
                *(ushort4*)&As[buf][rr][cc] = u0;
                *(ushort4*)&As[buf][rr][cc + 4] = u1;
            } else {
                gld16((const uint16_t*)ga.A + (size_t)(tm + rr) * Kd + kt * 64 + cc, &As[buf][rr][cc]);
            }
            gld16(Bw + (size_t)(tn + rr) * Kd + kt * 64 + cc, &Bs[buf][rr][cc]);
        }
    };

    stage(0, 0);
    __syncthreads();
    const int nk = Kd / 64;
    for (int kt = 0; kt < nk; ++kt) {
        int buf = kt & 1;
        if (kt + 1 < nk) stage(buf ^ 1, kt + 1);
#pragma unroll
        for (int kk = 0; kk < 2; ++kk) {
            bf8 af[4], bfr[4];
#pragma unroll
            for (int m = 0; m < 4; ++m)
                af[m] = *(const bf8*)&As[buf][wr * 64 + m * 16 + (lane & 15)][kk * 32 + (lane >> 4) * 8];
#pragma unroll
            for (int n = 0; n < 4; ++n)
                bfr[n] = *(const bf8*)&Bs[buf][wc * 64 + n * 16 + (lane & 15)][kk * 32 + (lane >> 4) * 8];
#pragma unroll
            for (int m = 0; m < 4; ++m)
#pragma unroll
                for (int n = 0; n < 4; ++n)
                    acc[m][n] = __builtin_amdgcn_mfma_f32_16x16x32_bf16(af[m], bfr[n], acc[m][n], 0, 0, 0);
        }
        __syncthreads();
    }

#pragma unroll
    for (int m = 0; m < 4; ++m) {
        int r0 = tm + wr * 64 + m * 16 + (lane >> 4) * 4;
#pragma unroll
        for (int n = 0; n < 4; ++n) {
            int c = tn + wc * 64 + n * 16 + (lane & 15);
            float bv = bias[c];
#pragma unroll
            for (int i = 0; i < 4; ++i) {
                int r = r0 + i;
                float v2 = (acc[m][n][i] + bv) * scale;
                if (mode == 4) {
                    ((uint16_t*)out)[(size_t)r * 1024 + c] = f2bf(v2);
                } else {
                    int b = r >> 10, l = r & 1023;
                    int h = c >> 6, d = c & 63;
                    size_t idx = (mode == 2)
                        ? (((size_t)(b * 16 + h) * 64 + d) * 1024 + l)
                        : (((size_t)(b * 16 + h) * 1024 + l) * 64 + d);
                    ((uint16_t*)out)[idx] = f2bf(v2);
                }
            }
        }
    }
}

// ---------------- fused scores + mask + softmax + PV ---------------------------
// Persistent: each block handles 16 q-tiles of ONE head (256 blocks = 1/CU).
// K and V fragments are q0-invariant per wave -> loaded ONCE per block into
// registers (kf+vf = 128 VGPR; launch_bounds(512,2)). Main loop has ZERO loads
// issued after stores -> NT store stream never blocks PV. Raw s_barrier +
// lgkmcnt-only waits.
#define QB 16
#define SROW 1048   // bf16 per row: 2096 B (16B aligned)
__global__ __launch_bounds__(512, 2) void attn_fused(
        const uint16_t* __restrict__ qh, const uint16_t* __restrict__ kh,
        const uint16_t* __restrict__ vt, const uint32_t* __restrict__ m2,
        float* __restrict__ attn_out, uint16_t* __restrict__ ctx) {
    __shared__ uint16_t P2[2][QB][SROW];             // 67 KB (unnormalized e)
    __shared__ __align__(16) float reds2[2][QB][8];
    __shared__ __align__(16) float invL2[2][QB];
    __shared__ float Opart2[2][QB][68];              // 8.7 KB
    const int tid = threadIdx.x, lane = tid & 63, w = tid >> 6;
    const int bid = blockIdx.x;                      // 256 blocks (1 per CU)
    const int j = bid >> 3;                          // [0,32)
    const int bh = (bid & 7) * 8 + (j >> 2);         // XCD-local head group
    const int qc0 = (j & 3) * 16;                    // 16 consecutive q-tiles
    const int b = bh >> 4, h = bh & 15;
    const int r = lane & 15, g = lane >> 4;
    const int nc0 = w * 128;
    const int dc = w & 3, khf = w >> 2;

    const uint16_t* K = kh + (size_t)bh * 1024 * 64;
    const uint16_t* V = vt + (size_t)bh * 64 * 1024;

    // ---- K fragments: loop-invariant, loaded ONCE per block (64 VGPR) ----
    bf8 kf[16];
#pragma unroll
    for (int cf = 0; cf < 8; ++cf) {
        const uint16_t* Kp = &K[(size_t)(nc0 + cf * 16 + r) * 64 + g * 8];
        kf[2 * cf]     = *(const bf8*)(Kp);
        kf[2 * cf + 1] = *(const bf8*)(Kp + 32);
    }
    // ---- V fragments: ALSO loop-invariant (dc,khf fixed per wave) -> once ----
    bf8 vf[16];
    {
        const uint16_t* Vp = &V[(size_t)(dc * 16 + r) * 1024 + khf * 512 + g * 8];
#pragma unroll
        for (int t = 0; t < 16; ++t)
            vf[t] = *(const bf8*)(Vp + t * 32);
    }

    // phase1: scores -> mask -> exp -> pack into P2[X] -> partial sums
    auto phase1 = [&](bf8 aq0, bf8 aq1, uint32_t mb, int X) {
        float sum = 0.f;
        char* prow = (char*)&P2[X][r][0];
#pragma unroll
        for (int cf = 0; cf < 8; ++cf) {
            f32x4 s = {};
            s = __builtin_amdgcn_mfma_f32_16x16x32_bf16(kf[2 * cf],     aq0, s, 0, 0, 0);
            s = __builtin_amdgcn_mfma_f32_16x16x32_bf16(kf[2 * cf + 1], aq1, s, 0, 0, 0);
            s[0] = ((mb >> (cf * 4)) & 1u) ? -__builtin_inff() : s[0];
            s[1] = ((mb >> (cf * 4 + 1)) & 1u) ? -__builtin_inff() : s[1];
            s[2] = ((mb >> (cf * 4 + 2)) & 1u) ? -__builtin_inff() : s[2];
            s[3] = ((mb >> (cf * 4 + 3)) & 1u) ? -__builtin_inff() : s[3];
            float e0 = __expf(s[0]);
            float e1 = __expf(s[1]);
            float e2 = __expf(s[2]);
            float e3 = __expf(s[3]);
            sum += (e0 + e1) + (e2 + e3);
            uint2 pk;
            pk.x = (uint32_t)f2bf(e0) | ((uint32_t)f2bf(e1) << 16);
            pk.y = (uint32_t)f2bf(e2) | ((uint32_t)f2bf(e3) << 16);
            *(uint2*)(prow + (size_t)(nc0 + cf * 16 + g * 4) * 2) = pk;
        }
        sum += __shfl_xor(sum, 16);
        sum += __shfl_xor(sum, 32);
        if (lane < 16) reds2[X][r][w] = sum;
    };

    // ---- prefetch pair-0 Q/mask ----
    int q0A = qc0 * 16, q0B = q0A + 16;
    const uint16_t* QA = qh + ((size_t)bh * 1024 + q0A) * 64;
    const uint16_t* QB_ = qh + ((size_t)bh * 1024 + q0B) * 64;
    bf8 aqA0 = *(const bf8*)&QA[(size_t)r * 64 + g * 8];
    bf8 aqA1 = *(const bf8*)&QA[(size_t)r * 64 + 32 + g * 8];
    bf8 aqB0 = *(const bf8*)&QB_[(size_t)r * 64 + g * 8];
    bf8 aqB1 = *(const bf8*)&QB_[(size_t)r * 64 + 32 + g * 8];
    uint32_t mbA = m2[((size_t)(b * 1024 + q0A + r) * 8 + w) * 4 + g];
    uint32_t mbB = m2[((size_t)(b * 1024 + q0B + r) * 8 + w) * 4 + g];

#pragma unroll 2
    for (int it = 0; it < 8; ++it) {
        q0A = (qc0 + 2 * it) * 16;
        q0B = q0A + 16;

        phase1(aqA0, aqA1, mbA, 0);
        phase1(aqB0, aqB1, mbB, 1);
        asm volatile("s_waitcnt lgkmcnt(0)" ::: "memory");
        __builtin_amdgcn_s_barrier();                            // BAR 1

        if (w < 2 && lane < 16) {
            float4 a = *(const float4*)&reds2[w][r][0];
            float4 c = *(const float4*)&reds2[w][r][4];
            invL2[w][r] = 1.f / (((a.x + a.y) + (a.z + a.w)) + ((c.x + c.y) + (c.z + c.w)));
        }

        // PV double: V in registers (vf), P from LDS -- no global loads here
        f32x4 oA = {}, oB = {};
        {
            const char* PrdA = (const char*)&P2[0][r][0] + khf * 1024 + g * 16;
            const char* PrdB = (const char*)&P2[1][r][0] + khf * 1024 + g * 16;
#pragma unroll
            for (int tt = 0; tt < 16; ++tt) {
                bf8 apA = *(const bf8*)(PrdA + tt * 64);
                bf8 apB = *(const bf8*)(PrdB + tt * 64);
                oA = __builtin_amdgcn_mfma_f32_16x16x32_bf16(apA, vf[tt], oA, 0, 0, 0);
                oB = __builtin_amdgcn_mfma_f32_16x16x32_bf16(apB, vf[tt], oB, 0, 0, 0);
            }
        }
        if (khf == 1) {
#pragma unroll
            for (int i = 0; i < 4; ++i) {
                Opart2[0][g * 4 + i][dc * 16 + r] = oA[i];
                Opart2[1][g * 4 + i][dc * 16 + r] = oB[i];
            }
        }
        asm volatile("s_waitcnt lgkmcnt(0)" ::: "memory");
        __builtin_amdgcn_s_barrier();                            // BAR 2

        // ---- prefetch next pair's Q/mask BEFORE any stores (loads precede
        //      stores in issue order -> their waits never require store drain)
        if (it < 7) {
            int q1A = (qc0 + 2 * (it + 1)) * 16, q1B = q1A + 16;
            const uint16_t* QnA = qh + ((size_t)bh * 1024 + q1A) * 64;
            const uint16_t* QnB = qh + ((size_t)bh * 1024 + q1B) * 64;
            aqA0 = *(const bf8*)&QnA[(size_t)r * 64 + g * 8];
            aqA1 = *(const bf8*)&QnA[(size_t)r * 64 + 32 + g * 8];
            aqB0 = *(const bf8*)&QnB[(size_t)r * 64 + g * 8];
            aqB1 = *(const bf8*)&QnB[(size_t)r * 64 + 32 + g * 8];
            mbA = m2[((size_t)(b * 1024 + q1A + r) * 8 + w) * 4 + g];
            mbB = m2[((size_t)(b * 1024 + q1B + r) * 8 + w) * 4 + g];
        }

        // ctx writes (normalized), both tiles
        if (khf == 0) {
            int d = h * 64 + dc * 16 + r;
            f32x4 ivA = *(const f32x4*)&invL2[0][g * 4];
            f32x4 ivB = *(const f32x4*)&invL2[1][g * 4];
#pragma unroll
            for (int i = 0; i < 4; ++i) {
                int qrA = q0A + g * 4 + i;
                int qrB = q0B + g * 4 + i;
                float vA = (oA[i] + Opart2[0][g * 4 + i][dc * 16 + r]) * ivA[i];
                float vB = (oB[i] + Opart2[1][g * 4 + i][dc * 16 + r]) * ivB[i];
                ctx[(size_t)(b * 1024 + qrA) * 1024 + d] = f2bf(vA);
                ctx[(size_t)(b * 1024 + qrB) * 1024 + d] = f2bf(vB);
            }
        }

        // attn stores: both tiles, rows {2w,2w+1}, 1KB-coalesced NT stores
#pragma unroll
        for (int X = 0; X < 2; ++X) {
            int q0X = X ? q0B : q0A;
            float* arow = attn_out + (((size_t)(h * 4 + b) * 1024) + q0X) * 1024;
#pragma unroll
            for (int rr = 0; rr < 2; ++rr) {
                int row = w * 2 + rr;
                float inv = invL2[X][row];
                const uint16_t* Pr = &P2[X][row][0];
                float* ar = arow + (size_t)row * 1024;
#pragma unroll
                for (int jj = 0; jj < 4; ++jj) {
                    int kx = jj * 256 + lane * 4;
                    uint2 sv = *(const uint2*)&Pr[kx];
                    f32x4 ov;
                    ov[0] = bf2f(sv.x & 0xffffu) * inv;
                    ov[1] = bf2f(sv.x >> 16) * inv;
                    ov[2] = bf2f(sv.y & 0xffffu) * inv;
                    ov[3] = bf2f(sv.y >> 16) * inv;
                    __builtin_nontemporal_store(ov, (f32x4*)&ar[kx]);
                }
            }
        }
        asm volatile("s_waitcnt lgkmcnt(0)" ::: "memory");
        __builtin_amdgcn_s_barrier();                            // BAR 3 (no vmcnt drain)
    }
}

// ---------------- residual + LayerNorm (bf16 FC input) --------------------------
__global__ __launch_bounds__(256) void fc_ln(
        const uint16_t* __restrict__ fcob, const float* __restrict__ resid,
        const float* __restrict__ g, const float* __restrict__ bb,
        float* __restrict__ y) {
    const int r = blockIdx.x, tid = threadIdx.x;
    const int lane = tid & 63, w = tid >> 6;
    __shared__ float red[8];
    ushort4 xv = ((const ushort4*)(fcob + (size_t)r * 1024))[tid];
    float4 rv = ((const float4*)(resid + (size_t)r * 1024))[tid];
    float x[4] = {bf2f(xv.x) + rv.x, bf2f(xv.y) + rv.y,
                  bf2f(xv.z) + rv.z, bf2f(xv.w) + rv.w};
    float s = x[0] + x[1] + x[2] + x[3];
    float s2 = x[0] * x[0] + x[1] * x[1] + x[2] * x[2] + x[3] * x[3];
#pragma unroll
    for (int off = 32; off; off >>= 1) { s += __shfl_xor(s, off); s2 += __shfl_xor(s2, off); }
    if (lane == 0) { red[w] = s; red[4 + w] = s2; }
    __syncthreads();
    s = red[0] + red[1] + red[2] + red[3];
    s2 = red[4] + red[5] + red[6] + red[7];
    float mu = s * (1.f / 1024.f);
    float var = s2 * (1.f / 1024.f) - mu * mu;
    float inv = rsqrtf(var + LN_EPS);
    float4 gv = ((const float4*)g)[tid];
    float4 bv = ((const float4*)bb)[tid];
    float4 ov;
    ov.x = (x[0] - mu) * inv * gv.x + bv.x;
    ov.y = (x[1] - mu) * inv * gv.y + bv.y;
    ov.z = (x[2] - mu) * inv * gv.z + bv.z;
    ov.w = (x[3] - mu) * inv * gv.w + bv.w;
    ((float4*)(y + (size_t)r * 1024))[tid] = ov;
}

extern "C" void kernel_launch(void* const* d_in, const int* in_sizes, int n_in,
                              void* d_out, int out_size, void* d_ws, size_t ws_size,
                              hipStream_t stream) {
    const float* q    = (const float*)d_in[0];
    const float* k    = (const float*)d_in[1];
    const float* v    = (const float*)d_in[2];
    const int*   mask = (const int*)d_in[3];
    const float* wq_w = (const float*)d_in[4];
    const float* wq_b = (const float*)d_in[5];
    const float* wk_w = (const float*)d_in[6];
    const float* wk_b = (const float*)d_in[7];
    const float* wv_w = (const float*)d_in[8];
    const float* wv_b = (const float*)d_in[9];
    const float* fc_w = (const float*)d_in[10];
    const float* fc_b = (const float*)d_in[11];
    const float* ln_g = (const float*)d_in[12];
    const float* ln_b = (const float*)d_in[13];

    char* ws = (char*)d_ws;
    uint16_t* wqb = (uint16_t*)(ws + (24u << 20));      // 2 MB each
    uint16_t* wkb = (uint16_t*)(ws + (26u << 20));
    uint16_t* wvb = (uint16_t*)(ws + (28u << 20));
    uint16_t* wfb = (uint16_t*)(ws + (30u << 20));
    uint16_t* qhb = (uint16_t*)(ws + (32u << 20));      // [bh][l][64]
    uint16_t* khb = (uint16_t*)(ws + (40u << 20));
    uint16_t* vtb = (uint16_t*)(ws + (48u << 20));      // [bh][d][l]
    uint16_t* ctx = (uint16_t*)(ws + (56u << 20));      // [b*l][1024]
    uint16_t* fcb = (uint16_t*)(ws + (64u << 20));      // 8 MB bf16 FC out
    uint32_t* m2  = (uint32_t*)(ws + (80u << 20));      // 512 KB mask bits

    float* y_out = (float*)d_out;
    float* attn_out = y_out + (size_t)4 * 1024 * 1024;

    cvt_bf16<<<dim3(64, 1, 4), 256, 0, stream>>>(wq_w, wk_w, wv_w, fc_w, wqb, wkb, wvb, wfb, (1 << 20) / 4);
    mask_bits<<<512, 256, 0, stream>>>(mask, m2);

    GArgs3 qkv;
    qkv.g[0] = {q, wqb, wq_b, qhb, 0, 1, 0.125f};
    qkv.g[1] = {k, wkb, wk_b, khb, 0, 1, 1.0f};
    qkv.g[2] = {v, wvb, wv_b, vtb, 2, 1, 1.0f};
    gemm_bt<<<dim3(8, 32, 3), 256, 0, stream>>>(qkv, 1024);

    attn_fused<<<256, 512, 0, stream>>>(qhb, khb, vtb, m2, attn_out, ctx);

    GArgs3 fc;
    fc.g[0] = {ctx, wfb, fc_b, fcb, 4, 0, 1.0f};
    fc.g[1] = fc.g[0]; fc.g[2] = fc.g[0];
    gemm_bt<<<dim3(8, 32, 1), 256, 0, stream>>>(fc, 1024);

    fc_ln<<<4096, 256, 0, stream>>>(fcb, q, ln_g, ln_b, y_out);
}

// Round 19
// 174.643 us; speedup vs baseline: 1.2124x; 1.2124x over previous
//
#include <hip/hip_runtime.h>
#include <hip/hip_bf16.h>
#include <stdint.h>

typedef short bf8 __attribute__((ext_vector_type(8)));     // 8 x bf16 (4 VGPR)
typedef float f32x4 __attribute__((ext_vector_type(4)));

#define LN_EPS 1e-5f

__device__ __forceinline__ uint16_t f2bf(float f) {
    __hip_bfloat16 h = __float2bfloat16(f);           // RNE
    return __builtin_bit_cast(uint16_t, h);
}
__device__ __forceinline__ float bf2f(uint32_t u) {
    return __uint_as_float(u << 16);
}

__device__ __forceinline__ void gld16(const void* g, void* l) {
    __builtin_amdgcn_global_load_lds(
        (const __attribute__((address_space(1))) uint32_t*)(uintptr_t)g,
        (__attribute__((address_space(3))) uint32_t*)(uint32_t)(uintptr_t)l,
        16, 0, 0);
}

// ---------------- fp32 -> bf16 convert (up to 4 arrays per launch) -------------
__global__ void cvt_bf16(const float* __restrict__ s0, const float* __restrict__ s1,
                         const float* __restrict__ s2, const float* __restrict__ s3,
                         uint16_t* d0, uint16_t* d1, uint16_t* d2, uint16_t* d3, int n4) {
    const float* ss[4] = {s0, s1, s2, s3};
    uint16_t*    dd[4] = {d0, d1, d2, d3};
    const float* s = ss[blockIdx.z];
    uint16_t*    d = dd[blockIdx.z];
    int i = blockIdx.x * blockDim.x + threadIdx.x;
    int stride = gridDim.x * blockDim.x;
    for (; i < n4; i += stride) {
        float4 f = ((const float4*)s)[i];
        ushort4 u;
        u.x = f2bf(f.x); u.y = f2bf(f.y); u.z = f2bf(f.z); u.w = f2bf(f.w);
        ((ushort4*)d)[i] = u;
    }
}

// ---------------- mask -> per-lane bit words -----------------------------------
// m2[((b*1024+row)*8 + w)*4 + g], bit (cf*4+i) = mask[b][row][w*128+cf*16+g*4+i]
__global__ __launch_bounds__(256) void mask_bits(const int* __restrict__ mask,
                                                 uint32_t* __restrict__ m2) {
    int idx = blockIdx.x * 256 + threadIdx.x;   // 131072 words
    int b = idx >> 15, row = (idx >> 5) & 1023, w = (idx >> 2) & 7, g = idx & 3;
    const int* mrow = mask + ((size_t)b * 1024 + row) * 1024 + w * 128 + g * 4;
    uint32_t bits = 0;
#pragma unroll
    for (int cf = 0; cf < 8; ++cf) {
        int4 mv = *(const int4*)&mrow[cf * 16];
        bits |= (mv.x ? 1u : 0u) << (cf * 4);
        bits |= (mv.y ? 1u : 0u) << (cf * 4 + 1);
        bits |= (mv.z ? 1u : 0u) << (cf * 4 + 2);
        bits |= (mv.w ? 1u : 0u) << (cf * 4 + 3);
    }
    m2[idx] = bits;
}

// ---------------- GEMM: C[r][c] = (sum_d A[r][d]*W[c][d] + bias[c]) * scale ----
// mode 0: bf16 head layout; mode 2: bf16 V-transposed; mode 3: fp32 plain;
// mode 4: bf16 plain [r*1024+c]
struct GArgs { const uint16_t* A; const uint16_t* W; const float* bias; void* out; int mode; float scale; };
struct GArgs3 { GArgs g[3]; };

__global__ __launch_bounds__(256) void gemm_bt(GArgs3 args, int Kd) {
    const GArgs ga = args.g[blockIdx.z];
    const uint16_t* __restrict__ A  = ga.A;
    const uint16_t* __restrict__ Bw = ga.W;
    const float* __restrict__ bias  = ga.bias;
    void* __restrict__ out = ga.out;
    const int mode = ga.mode;
    const float scale = ga.scale;

    __shared__ uint16_t As[2][128][64];
    __shared__ uint16_t Bs[2][128][64];
    const int tid = threadIdx.x;
    const int lane = tid & 63, w = tid >> 6;
    const int wr = w >> 1, wc = w & 1;
    const int tm = blockIdx.y * 128, tn = blockIdx.x * 128;

    f32x4 acc[4][4] = {};

    auto stage = [&](int buf, int kt) {
#pragma unroll
        for (int j = 0; j < 4; ++j) {
            int rr = (w * 4 + j) * 8 + (lane >> 3);
            int cc = (lane & 7) * 8;
            gld16(A + (size_t)(tm + rr) * Kd + kt * 64 + cc, &As[buf][rr][cc]);
            gld16(Bw + (size_t)(tn + rr) * Kd + kt * 64 + cc, &Bs[buf][rr][cc]);
        }
    };

    stage(0, 0);
    __syncthreads();
    const int nk = Kd / 64;
    for (int kt = 0; kt < nk; ++kt) {
        int buf = kt & 1;
        if (kt + 1 < nk) stage(buf ^ 1, kt + 1);
#pragma unroll
        for (int kk = 0; kk < 2; ++kk) {
            bf8 af[4], bfr[4];
#pragma unroll
            for (int m = 0; m < 4; ++m)
                af[m] = *(const bf8*)&As[buf][wr * 64 + m * 16 + (lane & 15)][kk * 32 + (lane >> 4) * 8];
#pragma unroll
            for (int n = 0; n < 4; ++n)
                bfr[n] = *(const bf8*)&Bs[buf][wc * 64 + n * 16 + (lane & 15)][kk * 32 + (lane >> 4) * 8];
#pragma unroll
            for (int m = 0; m < 4; ++m)
#pragma unroll
                for (int n = 0; n < 4; ++n)
                    acc[m][n] = __builtin_amdgcn_mfma_f32_16x16x32_bf16(af[m], bfr[n], acc[m][n], 0, 0, 0);
        }
        __syncthreads();
    }

#pragma unroll
    for (int m = 0; m < 4; ++m) {
        int r0 = tm + wr * 64 + m * 16 + (lane >> 4) * 4;
#pragma unroll
        for (int n = 0; n < 4; ++n) {
            int c = tn + wc * 64 + n * 16 + (lane & 15);
            float bv = bias[c];
#pragma unroll
            for (int i = 0; i < 4; ++i) {
                int r = r0 + i;
                float v2 = (acc[m][n][i] + bv) * scale;
                if (mode == 3) {
                    ((float*)out)[(size_t)r * 1024 + c] = v2;
                } else if (mode == 4) {
                    ((uint16_t*)out)[(size_t)r * 1024 + c] = f2bf(v2);
                } else {
                    int b = r >> 10, l = r & 1023;
                    int h = c >> 6, d = c & 63;
                    size_t idx = (mode == 2)
                        ? (((size_t)(b * 16 + h) * 64 + d) * 1024 + l)
                        : (((size_t)(b * 16 + h) * 1024 + l) * 64 + d);
                    ((uint16_t*)out)[idx] = f2bf(v2);
                }
            }
        }
    }
}

// ---------------- fused scores + mask + softmax + PV ---------------------------
// Persistent: each block handles 16 q-tiles of ONE head (256 blocks = 1/CU).
// K and V fragments are q0-invariant per wave -> loaded ONCE per block into
// registers (kf+vf = 128 VGPR; launch_bounds(512,2)). Main loop has ZERO loads
// issued after stores -> NT store stream never blocks PV. Raw s_barrier +
// lgkmcnt-only waits.
#define QB 16
#define SROW 1048   // bf16 per row: 2096 B (16B aligned)
__global__ __launch_bounds__(512, 2) void attn_fused(
        const uint16_t* __restrict__ qh, const uint16_t* __restrict__ kh,
        const uint16_t* __restrict__ vt, const uint32_t* __restrict__ m2,
        float* __restrict__ attn_out, uint16_t* __restrict__ ctx) {
    __shared__ uint16_t P2[2][QB][SROW];             // 67 KB (unnormalized e)
    __shared__ __align__(16) float reds2[2][QB][8];
    __shared__ __align__(16) float invL2[2][QB];
    __shared__ float Opart2[2][QB][68];              // 8.7 KB
    const int tid = threadIdx.x, lane = tid & 63, w = tid >> 6;
    const int bid = blockIdx.x;                      // 256 blocks (1 per CU)
    const int j = bid >> 3;                          // [0,32)
    const int bh = (bid & 7) * 8 + (j >> 2);         // XCD-local head group
    const int qc0 = (j & 3) * 16;                    // 16 consecutive q-tiles
    const int b = bh >> 4, h = bh & 15;
    const int r = lane & 15, g = lane >> 4;
    const int nc0 = w * 128;
    const int dc = w & 3, khf = w >> 2;

    const uint16_t* K = kh + (size_t)bh * 1024 * 64;
    const uint16_t* V = vt + (size_t)bh * 64 * 1024;

    // ---- K fragments: loop-invariant, loaded ONCE per block (64 VGPR) ----
    bf8 kf[16];
#pragma unroll
    for (int cf = 0; cf < 8; ++cf) {
        const uint16_t* Kp = &K[(size_t)(nc0 + cf * 16 + r) * 64 + g * 8];
        kf[2 * cf]     = *(const bf8*)(Kp);
        kf[2 * cf + 1] = *(const bf8*)(Kp + 32);
    }
    // ---- V fragments: ALSO loop-invariant (dc,khf fixed per wave) -> once ----
    bf8 vf[16];
    {
        const uint16_t* Vp = &V[(size_t)(dc * 16 + r) * 1024 + khf * 512 + g * 8];
#pragma unroll
        for (int t = 0; t < 16; ++t)
            vf[t] = *(const bf8*)(Vp + t * 32);
    }

    // phase1: scores -> mask -> exp -> pack into P2[X] -> partial sums
    auto phase1 = [&](bf8 aq0, bf8 aq1, uint32_t mb, int X) {
        float sum = 0.f;
        char* prow = (char*)&P2[X][r][0];
#pragma unroll
        for (int cf = 0; cf < 8; ++cf) {
            f32x4 s = {};
            s = __builtin_amdgcn_mfma_f32_16x16x32_bf16(kf[2 * cf],     aq0, s, 0, 0, 0);
            s = __builtin_amdgcn_mfma_f32_16x16x32_bf16(kf[2 * cf + 1], aq1, s, 0, 0, 0);
            s[0] = ((mb >> (cf * 4)) & 1u) ? -__builtin_inff() : s[0];
            s[1] = ((mb >> (cf * 4 + 1)) & 1u) ? -__builtin_inff() : s[1];
            s[2] = ((mb >> (cf * 4 + 2)) & 1u) ? -__builtin_inff() : s[2];
            s[3] = ((mb >> (cf * 4 + 3)) & 1u) ? -__builtin_inff() : s[3];
            float e0 = __expf(s[0]);
            float e1 = __expf(s[1]);
            float e2 = __expf(s[2]);
            float e3 = __expf(s[3]);
            sum += (e0 + e1) + (e2 + e3);
            uint2 pk;
            pk.x = (uint32_t)f2bf(e0) | ((uint32_t)f2bf(e1) << 16);
            pk.y = (uint32_t)f2bf(e2) | ((uint32_t)f2bf(e3) << 16);
            *(uint2*)(prow + (size_t)(nc0 + cf * 16 + g * 4) * 2) = pk;
        }
        sum += __shfl_xor(sum, 16);
        sum += __shfl_xor(sum, 32);
        if (lane < 16) reds2[X][r][w] = sum;
    };

    // ---- prefetch pair-0 Q/mask ----
    int q0A = qc0 * 16, q0B = q0A + 16;
    const uint16_t* QA = qh + ((size_t)bh * 1024 + q0A) * 64;
    const uint16_t* QB_ = qh + ((size_t)bh * 1024 + q0B) * 64;
    bf8 aqA0 = *(const bf8*)&QA[(size_t)r * 64 + g * 8];
    bf8 aqA1 = *(const bf8*)&QA[(size_t)r * 64 + 32 + g * 8];
    bf8 aqB0 = *(const bf8*)&QB_[(size_t)r * 64 + g * 8];
    bf8 aqB1 = *(const bf8*)&QB_[(size_t)r * 64 + 32 + g * 8];
    uint32_t mbA = m2[((size_t)(b * 1024 + q0A + r) * 8 + w) * 4 + g];
    uint32_t mbB = m2[((size_t)(b * 1024 + q0B + r) * 8 + w) * 4 + g];

#pragma unroll 2
    for (int it = 0; it < 8; ++it) {
        q0A = (qc0 + 2 * it) * 16;
        q0B = q0A + 16;

        phase1(aqA0, aqA1, mbA, 0);
        phase1(aqB0, aqB1, mbB, 1);
        asm volatile("s_waitcnt lgkmcnt(0)" ::: "memory");
        __builtin_amdgcn_s_barrier();                            // BAR 1

        if (w < 2 && lane < 16) {
            float4 a = *(const float4*)&reds2[w][r][0];
            float4 c = *(const float4*)&reds2[w][r][4];
            invL2[w][r] = 1.f / (((a.x + a.y) + (a.z + a.w)) + ((c.x + c.y) + (c.z + c.w)));
        }

        // PV double: V in registers (vf), P from LDS -- no global loads here
        f32x4 oA = {}, oB = {};
        {
            const char* PrdA = (const char*)&P2[0][r][0] + khf * 1024 + g * 16;
            const char* PrdB = (const char*)&P2[1][r][0] + khf * 1024 + g * 16;
#pragma unroll
            for (int tt = 0; tt < 16; ++tt) {
                bf8 apA = *(const bf8*)(PrdA + tt * 64);
                bf8 apB = *(const bf8*)(PrdB + tt * 64);
                oA = __builtin_amdgcn_mfma_f32_16x16x32_bf16(apA, vf[tt], oA, 0, 0, 0);
                oB = __builtin_amdgcn_mfma_f32_16x16x32_bf16(apB, vf[tt], oB, 0, 0, 0);
            }
        }
        if (khf == 1) {
#pragma unroll
            for (int i = 0; i < 4; ++i) {
                Opart2[0][g * 4 + i][dc * 16 + r] = oA[i];
                Opart2[1][g * 4 + i][dc * 16 + r] = oB[i];
            }
        }
        asm volatile("s_waitcnt lgkmcnt(0)" ::: "memory");
        __builtin_amdgcn_s_barrier();                            // BAR 2

        // ---- prefetch next pair's Q/mask BEFORE any stores (loads precede
        //      stores in issue order -> their waits never require store drain)
        if (it < 7) {
            int q1A = (qc0 + 2 * (it + 1)) * 16, q1B = q1A + 16;
            const uint16_t* QnA = qh + ((size_t)bh * 1024 + q1A) * 64;
            const uint16_t* QnB = qh + ((size_t)bh * 1024 + q1B) * 64;
            aqA0 = *(const bf8*)&QnA[(size_t)r * 64 + g * 8];
            aqA1 = *(const bf8*)&QnA[(size_t)r * 64 + 32 + g * 8];
            aqB0 = *(const bf8*)&QnB[(size_t)r * 64 + g * 8];
            aqB1 = *(const bf8*)&QnB[(size_t)r * 64 + 32 + g * 8];
            mbA = m2[((size_t)(b * 1024 + q1A + r) * 8 + w) * 4 + g];
            mbB = m2[((size_t)(b * 1024 + q1B + r) * 8 + w) * 4 + g];
        }

        // ctx writes (normalized), both tiles
        if (khf == 0) {
            int d = h * 64 + dc * 16 + r;
            f32x4 ivA = *(const f32x4*)&invL2[0][g * 4];
            f32x4 ivB = *(const f32x4*)&invL2[1][g * 4];
#pragma unroll
            for (int i = 0; i < 4; ++i) {
                int qrA = q0A + g * 4 + i;
                int qrB = q0B + g * 4 + i;
                float vA = (oA[i] + Opart2[0][g * 4 + i][dc * 16 + r]) * ivA[i];
                float vB = (oB[i] + Opart2[1][g * 4 + i][dc * 16 + r]) * ivB[i];
                ctx[(size_t)(b * 1024 + qrA) * 1024 + d] = f2bf(vA);
                ctx[(size_t)(b * 1024 + qrB) * 1024 + d] = f2bf(vB);
            }
        }

        // attn stores: both tiles, rows {2w,2w+1}, 1KB-coalesced NT stores
#pragma unroll
        for (int X = 0; X < 2; ++X) {
            int q0X = X ? q0B : q0A;
            float* arow = attn_out + (((size_t)(h * 4 + b) * 1024) + q0X) * 1024;
#pragma unroll
            for (int rr = 0; rr < 2; ++rr) {
                int row = w * 2 + rr;
                float inv = invL2[X][row];
                const uint16_t* Pr = &P2[X][row][0];
                float* ar = arow + (size_t)row * 1024;
#pragma unroll
                for (int jj = 0; jj < 4; ++jj) {
                    int kx = jj * 256 + lane * 4;
                    uint2 sv = *(const uint2*)&Pr[kx];
                    f32x4 ov;
                    ov[0] = bf2f(sv.x & 0xffffu) * inv;
                    ov[1] = bf2f(sv.x >> 16) * inv;
                    ov[2] = bf2f(sv.y & 0xffffu) * inv;
                    ov[3] = bf2f(sv.y >> 16) * inv;
                    __builtin_nontemporal_store(ov, (f32x4*)&ar[kx]);
                }
            }
        }
        asm volatile("s_waitcnt lgkmcnt(0)" ::: "memory");
        __builtin_amdgcn_s_barrier();                            // BAR 3 (no vmcnt drain)
    }
}

// ---------------- residual + LayerNorm (bf16 FC input) --------------------------
__global__ __launch_bounds__(256) void fc_ln(
        const uint16_t* __restrict__ fcob, const float* __restrict__ resid,
        const float* __restrict__ g, const float* __restrict__ bb,
        float* __restrict__ y) {
    const int r = blockIdx.x, tid = threadIdx.x;
    const int lane = tid & 63, w = tid >> 6;
    __shared__ float red[8];
    ushort4 xv = ((const ushort4*)(fcob + (size_t)r * 1024))[tid];
    float4 rv = ((const float4*)(resid + (size_t)r * 1024))[tid];
    float x[4] = {bf2f(xv.x) + rv.x, bf2f(xv.y) + rv.y,
                  bf2f(xv.z) + rv.z, bf2f(xv.w) + rv.w};
    float s = x[0] + x[1] + x[2] + x[3];
    float s2 = x[0] * x[0] + x[1] * x[1] + x[2] * x[2] + x[3] * x[3];
#pragma unroll
    for (int off = 32; off; off >>= 1) { s += __shfl_xor(s, off); s2 += __shfl_xor(s2, off); }
    if (lane == 0) { red[w] = s; red[4 + w] = s2; }
    __syncthreads();
    s = red[0] + red[1] + red[2] + red[3];
    s2 = red[4] + red[5] + red[6] + red[7];
    float mu = s * (1.f / 1024.f);
    float var = s2 * (1.f / 1024.f) - mu * mu;
    float inv = rsqrtf(var + LN_EPS);
    float4 gv = ((const float4*)g)[tid];
    float4 bv = ((const float4*)bb)[tid];
    float4 ov;
    ov.x = (x[0] - mu) * inv * gv.x + bv.x;
    ov.y = (x[1] - mu) * inv * gv.y + bv.y;
    ov.z = (x[2] - mu) * inv * gv.z + bv.z;
    ov.w = (x[3] - mu) * inv * gv.w + bv.w;
    ((float4*)(y + (size_t)r * 1024))[tid] = ov;
}

extern "C" void kernel_launch(void* const* d_in, const int* in_sizes, int n_in,
                              void* d_out, int out_size, void* d_ws, size_t ws_size,
                              hipStream_t stream) {
    const float* q    = (const float*)d_in[0];
    const float* k    = (const float*)d_in[1];
    const float* v    = (const float*)d_in[2];
    const int*   mask = (const int*)d_in[3];
    const float* wq_w = (const float*)d_in[4];
    const float* wq_b = (const float*)d_in[5];
    const float* wk_w = (const float*)d_in[6];
    const float* wk_b = (const float*)d_in[7];
    const float* wv_w = (const float*)d_in[8];
    const float* wv_b = (const float*)d_in[9];
    const float* fc_w = (const float*)d_in[10];
    const float* fc_b = (const float*)d_in[11];
    const float* ln_g = (const float*)d_in[12];
    const float* ln_b = (const float*)d_in[13];

    char* ws = (char*)d_ws;
    uint16_t* qb  = (uint16_t*)(ws);                    // 8 MB bf16 q
    uint16_t* kb  = (uint16_t*)(ws + (8u << 20));
    uint16_t* vb  = (uint16_t*)(ws + (16u << 20));
    uint16_t* wqb = (uint16_t*)(ws + (24u << 20));      // 2 MB each
    uint16_t* wkb = (uint16_t*)(ws + (26u << 20));
    uint16_t* wvb = (uint16_t*)(ws + (28u << 20));
    uint16_t* wfb = (uint16_t*)(ws + (30u << 20));
    uint16_t* qhb = (uint16_t*)(ws + (32u << 20));      // [bh][l][64]
    uint16_t* khb = (uint16_t*)(ws + (40u << 20));
    uint16_t* vtb = (uint16_t*)(ws + (48u << 20));      // [bh][d][l]
    uint16_t* ctx = (uint16_t*)(ws + (56u << 20));      // [b*l][1024]
    uint16_t* fcb = (uint16_t*)(ws + (64u << 20));      // 8 MB bf16 FC out
    uint32_t* m2  = (uint32_t*)(ws + (80u << 20));      // 512 KB mask bits

    float* y_out = (float*)d_out;
    float* attn_out = y_out + (size_t)4 * 1024 * 1024;

    cvt_bf16<<<dim3(256, 1, 3), 256, 0, stream>>>(q, k, v, nullptr, qb, kb, vb, nullptr, (4 << 20) / 4);
    cvt_bf16<<<dim3(64, 1, 4), 256, 0, stream>>>(wq_w, wk_w, wv_w, fc_w, wqb, wkb, wvb, wfb, (1 << 20) / 4);
    mask_bits<<<512, 256, 0, stream>>>(mask, m2);

    GArgs3 qkv;
    qkv.g[0] = {qb, wqb, wq_b, qhb, 0, 0.125f};
    qkv.g[1] = {kb, wkb, wk_b, khb, 0, 1.0f};
    qkv.g[2] = {vb, wvb, wv_b, vtb, 2, 1.0f};
    gemm_bt<<<dim3(8, 32, 3), 256, 0, stream>>>(qkv, 1024);

    attn_fused<<<256, 512, 0, stream>>>(qhb, khb, vtb, m2, attn_out, ctx);

    GArgs3 fc;
    fc.g[0] = {ctx, wfb, fc_b, fcb, 4, 1.0f};
    fc.g[1] = fc.g[0]; fc.g[2] = fc.g[0];
    gemm_bt<<<dim3(8, 32, 1), 256, 0, stream>>>(fc, 1024);

    fc_ln<<<4096, 256, 0, stream>>>(fcb, q, ln_g, ln_b, y_out);
}

// Round 20
// 163.242 us; speedup vs baseline: 1.2971x; 1.0698x over previous
//
#include <hip/hip_runtime.h>
#include <hip/hip_bf16.h>
#include <stdint.h>

typedef short bf8 __attribute__((ext_vector_type(8)));     // 8 x bf16 (4 VGPR)
typedef float f32x4 __attribute__((ext_vector_type(4)));

#define LN_EPS 1e-5f

__device__ __forceinline__ uint16_t f2bf(float f) {
    __hip_bfloat16 h = __float2bfloat16(f);           // RNE
    return __builtin_bit_cast(uint16_t, h);
}
__device__ __forceinline__ float bf2f(uint32_t u) {
    return __uint_as_float(u << 16);
}

__device__ __forceinline__ void gld16(const void* g, void* l) {
    __builtin_amdgcn_global_load_lds(
        (const __attribute__((address_space(1))) uint32_t*)(uintptr_t)g,
        (__attribute__((address_space(3))) uint32_t*)(uint32_t)(uintptr_t)l,
        16, 0, 0);
}

// ---------------- merged prologue: q/k/v cvt + weight cvt + mask bit-pack -------
// bid 0..767   : q/k/v fp32->bf16 (256 blocks each, 1M float4 each)
// bid 768..1023: wq/wk/wv/fc_w cvt (64 blocks each, 256K float4 each)
// bid 1024..1535: mask -> per-lane bit words (131072 words)
__global__ __launch_bounds__(256) void prep(
        const float* __restrict__ q, const float* __restrict__ k,
        const float* __restrict__ v,
        const float* __restrict__ wq, const float* __restrict__ wk,
        const float* __restrict__ wv, const float* __restrict__ fw,
        const int* __restrict__ mask,
        uint16_t* qb, uint16_t* kb, uint16_t* vb,
        uint16_t* wqb, uint16_t* wkb, uint16_t* wvb, uint16_t* wfb,
        uint32_t* __restrict__ m2) {
    const int bid = blockIdx.x;
    if (bid < 768) {
        const int which = bid >> 8, lb = bid & 255;
        const float* s = which == 0 ? q : which == 1 ? k : v;
        uint16_t*    d = which == 0 ? qb : which == 1 ? kb : vb;
        const int n4 = (4 << 20) / 4;
        for (int i = lb * 256 + threadIdx.x; i < n4; i += 65536) {
            float4 f = ((const float4*)s)[i];
            ushort4 u;
            u.x = f2bf(f.x); u.y = f2bf(f.y); u.z = f2bf(f.z); u.w = f2bf(f.w);
            ((ushort4*)d)[i] = u;
        }
    } else if (bid < 1024) {
        const int which = (bid - 768) >> 6, lb = (bid - 768) & 63;
        const float* s = which == 0 ? wq : which == 1 ? wk : which == 2 ? wv : fw;
        uint16_t*    d = which == 0 ? wqb : which == 1 ? wkb : which == 2 ? wvb : wfb;
        const int n4 = (1 << 20) / 4;
        for (int i = lb * 256 + threadIdx.x; i < n4; i += 16384) {
            float4 f = ((const float4*)s)[i];
            ushort4 u;
            u.x = f2bf(f.x); u.y = f2bf(f.y); u.z = f2bf(f.z); u.w = f2bf(f.w);
            ((ushort4*)d)[i] = u;
        }
    } else {
        int idx = (bid - 1024) * 256 + threadIdx.x;   // 131072 words
        int b = idx >> 15, row = (idx >> 5) & 1023, w = (idx >> 2) & 7, g = idx & 3;
        const int* mrow = mask + ((size_t)b * 1024 + row) * 1024 + w * 128 + g * 4;
        uint32_t bits = 0;
#pragma unroll
        for (int cf = 0; cf < 8; ++cf) {
            int4 mv = *(const int4*)&mrow[cf * 16];
            bits |= (mv.x ? 1u : 0u) << (cf * 4);
            bits |= (mv.y ? 1u : 0u) << (cf * 4 + 1);
            bits |= (mv.z ? 1u : 0u) << (cf * 4 + 2);
            bits |= (mv.w ? 1u : 0u) << (cf * 4 + 3);
        }
        m2[idx] = bits;
    }
}

// ---------------- GEMM: C[r][c] = (sum_d A[r][d]*W[c][d] + bias[c]) * scale ----
// mode 0: bf16 head layout; mode 2: bf16 V-transposed; mode 4: bf16 plain.
struct GArgs { const uint16_t* A; const uint16_t* W; const float* bias; void* out; int mode; float scale; };
struct GArgs3 { GArgs g[3]; };

__global__ __launch_bounds__(256) void gemm_bt(GArgs3 args, int Kd) {
    const GArgs ga = args.g[blockIdx.z];
    const uint16_t* __restrict__ A  = ga.A;
    const uint16_t* __restrict__ Bw = ga.W;
    const float* __restrict__ bias  = ga.bias;
    void* __restrict__ out = ga.out;
    const int mode = ga.mode;
    const float scale = ga.scale;

    __shared__ uint16_t As[2][128][64];
    __shared__ uint16_t Bs[2][128][64];
    const int tid = threadIdx.x;
    const int lane = tid & 63, w = tid >> 6;
    const int wr = w >> 1, wc = w & 1;
    const int tm = blockIdx.y * 128, tn = blockIdx.x * 128;

    f32x4 acc[4][4] = {};

    auto stage = [&](int buf, int kt) {
#pragma unroll
        for (int j = 0; j < 4; ++j) {
            int rr = (w * 4 + j) * 8 + (lane >> 3);
            int cc = (lane & 7) * 8;
            gld16(A + (size_t)(tm + rr) * Kd + kt * 64 + cc, &As[buf][rr][cc]);
            gld16(Bw + (size_t)(tn + rr) * Kd + kt * 64 + cc, &Bs[buf][rr][cc]);
        }
    };

    stage(0, 0);
    __syncthreads();
    const int nk = Kd / 64;
    for (int kt = 0; kt < nk; ++kt) {
        int buf = kt & 1;
        if (kt + 1 < nk) stage(buf ^ 1, kt + 1);
#pragma unroll
        for (int kk = 0; kk < 2; ++kk) {
            bf8 af[4], bfr[4];
#pragma unroll
            for (int m = 0; m < 4; ++m)
                af[m] = *(const bf8*)&As[buf][wr * 64 + m * 16 + (lane & 15)][kk * 32 + (lane >> 4) * 8];
#pragma unroll
            for (int n = 0; n < 4; ++n)
                bfr[n] = *(const bf8*)&Bs[buf][wc * 64 + n * 16 + (lane & 15)][kk * 32 + (lane >> 4) * 8];
#pragma unroll
            for (int m = 0; m < 4; ++m)
#pragma unroll
                for (int n = 0; n < 4; ++n)
                    acc[m][n] = __builtin_amdgcn_mfma_f32_16x16x32_bf16(af[m], bfr[n], acc[m][n], 0, 0, 0);
        }
        __syncthreads();
    }

#pragma unroll
    for (int m = 0; m < 4; ++m) {
        int r0 = tm + wr * 64 + m * 16 + (lane >> 4) * 4;
#pragma unroll
        for (int n = 0; n < 4; ++n) {
            int c = tn + wc * 64 + n * 16 + (lane & 15);
            float bv = bias[c];
#pragma unroll
            for (int i = 0; i < 4; ++i) {
                int r = r0 + i;
                float v2 = (acc[m][n][i] + bv) * scale;
                if (mode == 4) {
                    ((uint16_t*)out)[(size_t)r * 1024 + c] = f2bf(v2);
                } else {
                    int b = r >> 10, l = r & 1023;
                    int h = c >> 6, d = c & 63;
                    size_t idx = (mode == 2)
                        ? (((size_t)(b * 16 + h) * 64 + d) * 1024 + l)
                        : (((size_t)(b * 16 + h) * 1024 + l) * 64 + d);
                    ((uint16_t*)out)[idx] = f2bf(v2);
                }
            }
        }
    }
}

// ---------------- fused scores + mask + softmax + PV ---------------------------
// Persistent: each block handles 16 q-tiles of ONE head (256 blocks = 1/CU).
// K and V fragments are q0-invariant per wave -> loaded ONCE per block into
// registers (kf+vf = 128 VGPR; launch_bounds(512,2)). Main loop has ZERO loads
// issued after stores -> NT store stream never blocks PV. Raw s_barrier +
// lgkmcnt-only waits.
#define QB 16
#define SROW 1048   // bf16 per row: 2096 B (16B aligned)
__global__ __launch_bounds__(512, 2) void attn_fused(
        const uint16_t* __restrict__ qh, const uint16_t* __restrict__ kh,
        const uint16_t* __restrict__ vt, const uint32_t* __restrict__ m2,
        float* __restrict__ attn_out, uint16_t* __restrict__ ctx) {
    __shared__ uint16_t P2[2][QB][SROW];             // 67 KB (unnormalized e)
    __shared__ __align__(16) float reds2[2][QB][8];
    __shared__ __align__(16) float invL2[2][QB];
    __shared__ float Opart2[2][QB][68];              // 8.7 KB
    const int tid = threadIdx.x, lane = tid & 63, w = tid >> 6;
    const int bid = blockIdx.x;                      // 256 blocks (1 per CU)
    const int j = bid >> 3;                          // [0,32)
    const int bh = (bid & 7) * 8 + (j >> 2);         // XCD-local head group
    const int qc0 = (j & 3) * 16;                    // 16 consecutive q-tiles
    const int b = bh >> 4, h = bh & 15;
    const int r = lane & 15, g = lane >> 4;
    const int nc0 = w * 128;
    const int dc = w & 3, khf = w >> 2;

    const uint16_t* K = kh + (size_t)bh * 1024 * 64;
    const uint16_t* V = vt + (size_t)bh * 64 * 1024;

    // ---- K fragments: loop-invariant, loaded ONCE per block (64 VGPR) ----
    bf8 kf[16];
#pragma unroll
    for (int cf = 0; cf < 8; ++cf) {
        const uint16_t* Kp = &K[(size_t)(nc0 + cf * 16 + r) * 64 + g * 8];
        kf[2 * cf]     = *(const bf8*)(Kp);
        kf[2 * cf + 1] = *(const bf8*)(Kp + 32);
    }
    // ---- V fragments: ALSO loop-invariant (dc,khf fixed per wave) -> once ----
    bf8 vf[16];
    {
        const uint16_t* Vp = &V[(size_t)(dc * 16 + r) * 1024 + khf * 512 + g * 8];
#pragma unroll
        for (int t = 0; t < 16; ++t)
            vf[t] = *(const bf8*)(Vp + t * 32);
    }

    // phase1: scores -> mask -> exp -> pack into P2[X] -> partial sums
    auto phase1 = [&](bf8 aq0, bf8 aq1, uint32_t mb, int X) {
        float sum = 0.f;
        char* prow = (char*)&P2[X][r][0];
#pragma unroll
        for (int cf = 0; cf < 8; ++cf) {
            f32x4 s = {};
            s = __builtin_amdgcn_mfma_f32_16x16x32_bf16(kf[2 * cf],     aq0, s, 0, 0, 0);
            s = __builtin_amdgcn_mfma_f32_16x16x32_bf16(kf[2 * cf + 1], aq1, s, 0, 0, 0);
            s[0] = ((mb >> (cf * 4)) & 1u) ? -__builtin_inff() : s[0];
            s[1] = ((mb >> (cf * 4 + 1)) & 1u) ? -__builtin_inff() : s[1];
            s[2] = ((mb >> (cf * 4 + 2)) & 1u) ? -__builtin_inff() : s[2];
            s[3] = ((mb >> (cf * 4 + 3)) & 1u) ? -__builtin_inff() : s[3];
            float e0 = __expf(s[0]);
            float e1 = __expf(s[1]);
            float e2 = __expf(s[2]);
            float e3 = __expf(s[3]);
            sum += (e0 + e1) + (e2 + e3);
            uint2 pk;
            pk.x = (uint32_t)f2bf(e0) | ((uint32_t)f2bf(e1) << 16);
            pk.y = (uint32_t)f2bf(e2) | ((uint32_t)f2bf(e3) << 16);
            *(uint2*)(prow + (size_t)(nc0 + cf * 16 + g * 4) * 2) = pk;
        }
        sum += __shfl_xor(sum, 16);
        sum += __shfl_xor(sum, 32);
        if (lane < 16) reds2[X][r][w] = sum;
    };

    // ---- prefetch pair-0 Q/mask ----
    int q0A = qc0 * 16, q0B = q0A + 16;
    const uint16_t* QA = qh + ((size_t)bh * 1024 + q0A) * 64;
    const uint16_t* QB_ = qh + ((size_t)bh * 1024 + q0B) * 64;
    bf8 aqA0 = *(const bf8*)&QA[(size_t)r * 64 + g * 8];
    bf8 aqA1 = *(const bf8*)&QA[(size_t)r * 64 + 32 + g * 8];
    bf8 aqB0 = *(const bf8*)&QB_[(size_t)r * 64 + g * 8];
    bf8 aqB1 = *(const bf8*)&QB_[(size_t)r * 64 + 32 + g * 8];
    uint32_t mbA = m2[((size_t)(b * 1024 + q0A + r) * 8 + w) * 4 + g];
    uint32_t mbB = m2[((size_t)(b * 1024 + q0B + r) * 8 + w) * 4 + g];

#pragma unroll 2
    for (int it = 0; it < 8; ++it) {
        q0A = (qc0 + 2 * it) * 16;
        q0B = q0A + 16;

        phase1(aqA0, aqA1, mbA, 0);
        phase1(aqB0, aqB1, mbB, 1);
        asm volatile("s_waitcnt lgkmcnt(0)" ::: "memory");
        __builtin_amdgcn_s_barrier();                            // BAR 1

        if (w < 2 && lane < 16) {
            float4 a = *(const float4*)&reds2[w][r][0];
            float4 c = *(const float4*)&reds2[w][r][4];
            invL2[w][r] = 1.f / (((a.x + a.y) + (a.z + a.w)) + ((c.x + c.y) + (c.z + c.w)));
        }

        // PV double: V in registers (vf), P from LDS -- no global loads here
        f32x4 oA = {}, oB = {};
        {
            const char* PrdA = (const char*)&P2[0][r][0] + khf * 1024 + g * 16;
            const char* PrdB = (const char*)&P2[1][r][0] + khf * 1024 + g * 16;
#pragma unroll
            for (int tt = 0; tt < 16; ++tt) {
                bf8 apA = *(const bf8*)(PrdA + tt * 64);
                bf8 apB = *(const bf8*)(PrdB + tt * 64);
                oA = __builtin_amdgcn_mfma_f32_16x16x32_bf16(apA, vf[tt], oA, 0, 0, 0);
                oB = __builtin_amdgcn_mfma_f32_16x16x32_bf16(apB, vf[tt], oB, 0, 0, 0);
            }
        }
        if (khf == 1) {
#pragma unroll
            for (int i = 0; i < 4; ++i) {
                Opart2[0][g * 4 + i][dc * 16 + r] = oA[i];
                Opart2[1][g * 4 + i][dc * 16 + r] = oB[i];
            }
        }
        asm volatile("s_waitcnt lgkmcnt(0)" ::: "memory");
        __builtin_amdgcn_s_barrier();                            // BAR 2

        // ---- prefetch next pair's Q/mask BEFORE any stores (loads precede
        //      stores in issue order -> their waits never require store drain)
        if (it < 7) {
            int q1A = (qc0 + 2 * (it + 1)) * 16, q1B = q1A + 16;
            const uint16_t* QnA = qh + ((size_t)bh * 1024 + q1A) * 64;
            const uint16_t* QnB = qh + ((size_t)bh * 1024 + q1B) * 64;
            aqA0 = *(const bf8*)&QnA[(size_t)r * 64 + g * 8];
            aqA1 = *(const bf8*)&QnA[(size_t)r * 64 + 32 + g * 8];
            aqB0 = *(const bf8*)&QnB[(size_t)r * 64 + g * 8];
            aqB1 = *(const bf8*)&QnB[(size_t)r * 64 + 32 + g * 8];
            mbA = m2[((size_t)(b * 1024 + q1A + r) * 8 + w) * 4 + g];
            mbB = m2[((size_t)(b * 1024 + q1B + r) * 8 + w) * 4 + g];
        }

        // ctx writes (normalized), both tiles
        if (khf == 0) {
            int d = h * 64 + dc * 16 + r;
            f32x4 ivA = *(const f32x4*)&invL2[0][g * 4];
            f32x4 ivB = *(const f32x4*)&invL2[1][g * 4];
#pragma unroll
            for (int i = 0; i < 4; ++i) {
                int qrA = q0A + g * 4 + i;
                int qrB = q0B + g * 4 + i;
                float vA = (oA[i] + Opart2[0][g * 4 + i][dc * 16 + r]) * ivA[i];
                float vB = (oB[i] + Opart2[1][g * 4 + i][dc * 16 + r]) * ivB[i];
                ctx[(size_t)(b * 1024 + qrA) * 1024 + d] = f2bf(vA);
                ctx[(size_t)(b * 1024 + qrB) * 1024 + d] = f2bf(vB);
            }
        }

        // attn stores: both tiles, rows {2w,2w+1}, 1KB-coalesced NT stores
#pragma unroll
        for (int X = 0; X < 2; ++X) {
            int q0X = X ? q0B : q0A;
            float* arow = attn_out + (((size_t)(h * 4 + b) * 1024) + q0X) * 1024;
#pragma unroll
            for (int rr = 0; rr < 2; ++rr) {
                int row = w * 2 + rr;
                float inv = invL2[X][row];
                const uint16_t* Pr = &P2[X][row][0];
                float* ar = arow + (size_t)row * 1024;
#pragma unroll
                for (int jj = 0; jj < 4; ++jj) {
                    int kx = jj * 256 + lane * 4;
                    uint2 sv = *(const uint2*)&Pr[kx];
                    f32x4 ov;
                    ov[0] = bf2f(sv.x & 0xffffu) * inv;
                    ov[1] = bf2f(sv.x >> 16) * inv;
                    ov[2] = bf2f(sv.y & 0xffffu) * inv;
                    ov[3] = bf2f(sv.y >> 16) * inv;
                    __builtin_nontemporal_store(ov, (f32x4*)&ar[kx]);
                }
            }
        }
        asm volatile("s_waitcnt lgkmcnt(0)" ::: "memory");
        __builtin_amdgcn_s_barrier();                            // BAR 3 (no vmcnt drain)
    }
}

// ---------------- residual + LayerNorm (bf16 FC input) --------------------------
__global__ __launch_bounds__(256) void fc_ln(
        const uint16_t* __restrict__ fcob, const float* __restrict__ resid,
        const float* __restrict__ g, const float* __restrict__ bb,
        float* __restrict__ y) {
    const int r = blockIdx.x, tid = threadIdx.x;
    const int lane = tid & 63, w = tid >> 6;
    __shared__ float red[8];
    ushort4 xv = ((const ushort4*)(fcob + (size_t)r * 1024))[tid];
    float4 rv = ((const float4*)(resid + (size_t)r * 1024))[tid];
    float x[4] = {bf2f(xv.x) + rv.x, bf2f(xv.y) + rv.y,
                  bf2f(xv.z) + rv.z, bf2f(xv.w) + rv.w};
    float s = x[0] + x[1] + x[2] + x[3];
    float s2 = x[0] * x[0] + x[1] * x[1] + x[2] * x[2] + x[3] * x[3];
#pragma unroll
    for (int off = 32; off; off >>= 1) { s += __shfl_xor(s, off); s2 += __shfl_xor(s2, off); }
    if (lane == 0) { red[w] = s; red[4 + w] = s2; }
    __syncthreads();
    s = red[0] + red[1] + red[2] + red[3];
    s2 = red[4] + red[5] + red[6] + red[7];
    float mu = s * (1.f / 1024.f);
    float var = s2 * (1.f / 1024.f) - mu * mu;
    float inv = rsqrtf(var + LN_EPS);
    float4 gv = ((const float4*)g)[tid];
    float4 bv = ((const float4*)bb)[tid];
    float4 ov;
    ov.x = (x[0] - mu) * inv * gv.x + bv.x;
    ov.y = (x[1] - mu) * inv * gv.y + bv.y;
    ov.z = (x[2] - mu) * inv * gv.z + bv.z;
    ov.w = (x[3] - mu) * inv * gv.w + bv.w;
    ((float4*)(y + (size_t)r * 1024))[tid] = ov;
}

extern "C" void kernel_launch(void* const* d_in, const int* in_sizes, int n_in,
                              void* d_out, int out_size, void* d_ws, size_t ws_size,
                              hipStream_t stream) {
    const float* q    = (const float*)d_in[0];
    const float* k    = (const float*)d_in[1];
    const float* v    = (const float*)d_in[2];
    const int*   mask = (const int*)d_in[3];
    const float* wq_w = (const float*)d_in[4];
    const float* wq_b = (const float*)d_in[5];
    const float* wk_w = (const float*)d_in[6];
    const float* wk_b = (const float*)d_in[7];
    const float* wv_w = (const float*)d_in[8];
    const float* wv_b = (const float*)d_in[9];
    const float* fc_w = (const float*)d_in[10];
    const float* fc_b = (const float*)d_in[11];
    const float* ln_g = (const float*)d_in[12];
    const float* ln_b = (const float*)d_in[13];

    char* ws = (char*)d_ws;
    uint16_t* qb  = (uint16_t*)(ws);                    // 8 MB bf16 q
    uint16_t* kb  = (uint16_t*)(ws + (8u << 20));
    uint16_t* vb  = (uint16_t*)(ws + (16u << 20));
    uint16_t* wqb = (uint16_t*)(ws + (24u << 20));      // 2 MB each
    uint16_t* wkb = (uint16_t*)(ws + (26u << 20));
    uint16_t* wvb = (uint16_t*)(ws + (28u << 20));
    uint16_t* wfb = (uint16_t*)(ws + (30u << 20));
    uint16_t* qhb = (uint16_t*)(ws + (32u << 20));      // [bh][l][64]
    uint16_t* khb = (uint16_t*)(ws + (40u << 20));
    uint16_t* vtb = (uint16_t*)(ws + (48u << 20));      // [bh][d][l]
    uint16_t* ctx = (uint16_t*)(ws + (56u << 20));      // [b*l][1024]
    uint16_t* fcb = (uint16_t*)(ws + (64u << 20));      // 8 MB bf16 FC out
    uint32_t* m2  = (uint32_t*)(ws + (80u << 20));      // 512 KB mask bits

    float* y_out = (float*)d_out;
    float* attn_out = y_out + (size_t)4 * 1024 * 1024;

    prep<<<1536, 256, 0, stream>>>(q, k, v, wq_w, wk_w, wv_w, fc_w, mask,
                                   qb, kb, vb, wqb, wkb, wvb, wfb, m2);

    GArgs3 qkv;
    qkv.g[0] = {qb, wqb, wq_b, qhb, 0, 0.125f};
    qkv.g[1] = {kb, wkb, wk_b, khb, 0, 1.0f};
    qkv.g[2] = {vb, wvb, wv_b, vtb, 2, 1.0f};
    gemm_bt<<<dim3(8, 32, 3), 256, 0, stream>>>(qkv, 1024);

    attn_fused<<<256, 512, 0, stream>>>(qhb, khb, vtb, m2, attn_out, ctx);

    GArgs3 fc;
    fc.g[0] = {ctx, wfb, fc_b, fcb, 4, 1.0f};
    fc.g[1] = fc.g[0]; fc.g[2] = fc.g[0];
    gemm_bt<<<dim3(8, 32, 1), 256, 0, stream>>>(fc, 1024);

    fc_ln<<<4096, 256, 0, stream>>>(fcb, q, ln_g, ln_b, y_out);
}

// Round 21
// 160.329 us; speedup vs baseline: 1.3206x; 1.0182x over previous
//
#include <hip/hip_runtime.h>
#include <hip/hip_bf16.h>
#include <stdint.h>

typedef short bf8 __attribute__((ext_vector_type(8)));     // 8 x bf16 (4 VGPR)
typedef float f32x4 __attribute__((ext_vector_type(4)));

#define LN_EPS 1e-5f

__device__ __forceinline__ uint16_t f2bf(float f) {
    __hip_bfloat16 h = __float2bfloat16(f);           // RNE
    return __builtin_bit_cast(uint16_t, h);
}
__device__ __forceinline__ float bf2f(uint32_t u) {
    return __uint_as_float(u << 16);
}

__device__ __forceinline__ void gld16(const void* g, void* l) {
    __builtin_amdgcn_global_load_lds(
        (const __attribute__((address_space(1))) uint32_t*)(uintptr_t)g,
        (__attribute__((address_space(3))) uint32_t*)(uint32_t)(uintptr_t)l,
        16, 0, 0);
}

// ---------------- merged prologue: q/k/v cvt + weight cvt + mask bit-pack -------
__global__ __launch_bounds__(256) void prep(
        const float* __restrict__ q, const float* __restrict__ k,
        const float* __restrict__ v,
        const float* __restrict__ wq, const float* __restrict__ wk,
        const float* __restrict__ wv, const float* __restrict__ fw,
        const int* __restrict__ mask,
        uint16_t* qb, uint16_t* kb, uint16_t* vb,
        uint16_t* wqb, uint16_t* wkb, uint16_t* wvb, uint16_t* wfb,
        uint32_t* __restrict__ m2) {
    const int bid = blockIdx.x;
    if (bid < 768) {
        const int which = bid >> 8, lb = bid & 255;
        const float* s = which == 0 ? q : which == 1 ? k : v;
        uint16_t*    d = which == 0 ? qb : which == 1 ? kb : vb;
        const int n4 = (4 << 20) / 4;
        for (int i = lb * 256 + threadIdx.x; i < n4; i += 65536) {
            float4 f = ((const float4*)s)[i];
            ushort4 u;
            u.x = f2bf(f.x); u.y = f2bf(f.y); u.z = f2bf(f.z); u.w = f2bf(f.w);
            ((ushort4*)d)[i] = u;
        }
    } else if (bid < 1024) {
        const int which = (bid - 768) >> 6, lb = (bid - 768) & 63;
        const float* s = which == 0 ? wq : which == 1 ? wk : which == 2 ? wv : fw;
        uint16_t*    d = which == 0 ? wqb : which == 1 ? wkb : which == 2 ? wvb : wfb;
        const int n4 = (1 << 20) / 4;
        for (int i = lb * 256 + threadIdx.x; i < n4; i += 16384) {
            float4 f = ((const float4*)s)[i];
            ushort4 u;
            u.x = f2bf(f.x); u.y = f2bf(f.y); u.z = f2bf(f.z); u.w = f2bf(f.w);
            ((ushort4*)d)[i] = u;
        }
    } else {
        int idx = (bid - 1024) * 256 + threadIdx.x;   // 131072 words
        int b = idx >> 15, row = (idx >> 5) & 1023, w = (idx >> 2) & 7, g = idx & 3;
        const int* mrow = mask + ((size_t)b * 1024 + row) * 1024 + w * 128 + g * 4;
        uint32_t bits = 0;
#pragma unroll
        for (int cf = 0; cf < 8; ++cf) {
            int4 mv = *(const int4*)&mrow[cf * 16];
            bits |= (mv.x ? 1u : 0u) << (cf * 4);
            bits |= (mv.y ? 1u : 0u) << (cf * 4 + 1);
            bits |= (mv.z ? 1u : 0u) << (cf * 4 + 2);
            bits |= (mv.w ? 1u : 0u) << (cf * 4 + 3);
        }
        m2[idx] = bits;
    }
}

// ---------------- GEMM: C[r][c] = (sum_d A[r][d]*W[c][d] + bias[c]) * scale ----
// mode 0: bf16 head layout; mode 2: bf16 V-transposed; mode 4: bf16 plain.
struct GArgs { const uint16_t* A; const uint16_t* W; const float* bias; void* out; int mode; float scale; };
struct GArgs3 { GArgs g[3]; };

__global__ __launch_bounds__(256) void gemm_bt(GArgs3 args, int Kd) {
    const GArgs ga = args.g[blockIdx.z];
    const uint16_t* __restrict__ A  = ga.A;
    const uint16_t* __restrict__ Bw = ga.W;
    const float* __restrict__ bias  = ga.bias;
    void* __restrict__ out = ga.out;
    const int mode = ga.mode;
    const float scale = ga.scale;

    __shared__ uint16_t As[2][128][64];
    __shared__ uint16_t Bs[2][128][64];
    const int tid = threadIdx.x;
    const int lane = tid & 63, w = tid >> 6;
    const int wr = w >> 1, wc = w & 1;
    const int tm = blockIdx.y * 128, tn = blockIdx.x * 128;

    f32x4 acc[4][4] = {};

    auto stage = [&](int buf, int kt) {
#pragma unroll
        for (int j = 0; j < 4; ++j) {
            int rr = (w * 4 + j) * 8 + (lane >> 3);
            int cc = (lane & 7) * 8;
            gld16(A + (size_t)(tm + rr) * Kd + kt * 64 + cc, &As[buf][rr][cc]);
            gld16(Bw + (size_t)(tn + rr) * Kd + kt * 64 + cc, &Bs[buf][rr][cc]);
        }
    };

    stage(0, 0);
    __syncthreads();
    const int nk = Kd / 64;
    for (int kt = 0; kt < nk; ++kt) {
        int buf = kt & 1;
        if (kt + 1 < nk) stage(buf ^ 1, kt + 1);
#pragma unroll
        for (int kk = 0; kk < 2; ++kk) {
            bf8 af[4], bfr[4];
#pragma unroll
            for (int m = 0; m < 4; ++m)
                af[m] = *(const bf8*)&As[buf][wr * 64 + m * 16 + (lane & 15)][kk * 32 + (lane >> 4) * 8];
#pragma unroll
            for (int n = 0; n < 4; ++n)
                bfr[n] = *(const bf8*)&Bs[buf][wc * 64 + n * 16 + (lane & 15)][kk * 32 + (lane >> 4) * 8];
#pragma unroll
            for (int m = 0; m < 4; ++m)
#pragma unroll
                for (int n = 0; n < 4; ++n)
                    acc[m][n] = __builtin_amdgcn_mfma_f32_16x16x32_bf16(af[m], bfr[n], acc[m][n], 0, 0, 0);
        }
        __syncthreads();
    }

#pragma unroll
    for (int m = 0; m < 4; ++m) {
        int r0 = tm + wr * 64 + m * 16 + (lane >> 4) * 4;
#pragma unroll
        for (int n = 0; n < 4; ++n) {
            int c = tn + wc * 64 + n * 16 + (lane & 15);
            float bv = bias[c];
#pragma unroll
            for (int i = 0; i < 4; ++i) {
                int r = r0 + i;
                float v2 = (acc[m][n][i] + bv) * scale;
                if (mode == 4) {
                    ((uint16_t*)out)[(size_t)r * 1024 + c] = f2bf(v2);
                } else {
                    int b = r >> 10, l = r & 1023;
                    int h = c >> 6, d = c & 63;
                    size_t idx = (mode == 2)
                        ? (((size_t)(b * 16 + h) * 64 + d) * 1024 + l)
                        : (((size_t)(b * 16 + h) * 1024 + l) * 64 + d);
                    ((uint16_t*)out)[idx] = f2bf(v2);
                }
            }
        }
    }
}

// ---------------- fused scores + mask + softmax + PV ---------------------------
// Persistent: 16 q-tiles of ONE head per block (256 blocks = 1/CU); K+V in
// registers. 4 P buffers (pair (it&1)*2) -> NO barrier after the store batch:
// stores of iter it overlap phase-1 MFMA of it+1. 2 barriers/iteration.
#define QB 16
#define SROW 1048   // bf16 per row: 2096 B (16B aligned)
__global__ __launch_bounds__(512, 2) void attn_fused(
        const uint16_t* __restrict__ qh, const uint16_t* __restrict__ kh,
        const uint16_t* __restrict__ vt, const uint32_t* __restrict__ m2,
        float* __restrict__ attn_out, uint16_t* __restrict__ ctx) {
    __shared__ uint16_t P2[4][QB][SROW];             // 134 KB (unnormalized e)
    __shared__ __align__(16) float reds2[2][QB][8];
    __shared__ __align__(16) float invL2[2][QB];
    __shared__ float Opart2[2][QB][68];              // 8.7 KB
    const int tid = threadIdx.x, lane = tid & 63, w = tid >> 6;
    const int bid = blockIdx.x;                      // 256 blocks (1 per CU)
    const int j = bid >> 3;                          // [0,32)
    const int bh = (bid & 7) * 8 + (j >> 2);         // XCD-local head group
    const int qc0 = (j & 3) * 16;                    // 16 consecutive q-tiles
    const int b = bh >> 4, h = bh & 15;
    const int r = lane & 15, g = lane >> 4;
    const int nc0 = w * 128;
    const int dc = w & 3, khf = w >> 2;

    const uint16_t* K = kh + (size_t)bh * 1024 * 64;
    const uint16_t* V = vt + (size_t)bh * 64 * 1024;

    // ---- K fragments: loop-invariant, loaded ONCE per block (64 VGPR) ----
    bf8 kf[16];
#pragma unroll
    for (int cf = 0; cf < 8; ++cf) {
        const uint16_t* Kp = &K[(size_t)(nc0 + cf * 16 + r) * 64 + g * 8];
        kf[2 * cf]     = *(const bf8*)(Kp);
        kf[2 * cf + 1] = *(const bf8*)(Kp + 32);
    }
    // ---- V fragments: ALSO loop-invariant (dc,khf fixed per wave) -> once ----
    bf8 vf[16];
    {
        const uint16_t* Vp = &V[(size_t)(dc * 16 + r) * 1024 + khf * 512 + g * 8];
#pragma unroll
        for (int t = 0; t < 16; ++t)
            vf[t] = *(const bf8*)(Vp + t * 32);
    }

    // phase1: scores -> mask -> exp -> pack into P2[buf] -> partial sums (reds2[pos])
    auto phase1 = [&](bf8 aq0, bf8 aq1, uint32_t mb, int buf, int pos) {
        float sum = 0.f;
        char* prow = (char*)&P2[buf][r][0];
#pragma unroll
        for (int cf = 0; cf < 8; ++cf) {
            f32x4 s = {};
            s = __builtin_amdgcn_mfma_f32_16x16x32_bf16(kf[2 * cf],     aq0, s, 0, 0, 0);
            s = __builtin_amdgcn_mfma_f32_16x16x32_bf16(kf[2 * cf + 1], aq1, s, 0, 0, 0);
            s[0] = ((mb >> (cf * 4)) & 1u) ? -__builtin_inff() : s[0];
            s[1] = ((mb >> (cf * 4 + 1)) & 1u) ? -__builtin_inff() : s[1];
            s[2] = ((mb >> (cf * 4 + 2)) & 1u) ? -__builtin_inff() : s[2];
            s[3] = ((mb >> (cf * 4 + 3)) & 1u) ? -__builtin_inff() : s[3];
            float e0 = __expf(s[0]);
            float e1 = __expf(s[1]);
            float e2 = __expf(s[2]);
            float e3 = __expf(s[3]);
            sum += (e0 + e1) + (e2 + e3);
            uint2 pk;
            pk.x = (uint32_t)f2bf(e0) | ((uint32_t)f2bf(e1) << 16);
            pk.y = (uint32_t)f2bf(e2) | ((uint32_t)f2bf(e3) << 16);
            *(uint2*)(prow + (size_t)(nc0 + cf * 16 + g * 4) * 2) = pk;
        }
        sum += __shfl_xor(sum, 16);
        sum += __shfl_xor(sum, 32);
        if (lane < 16) reds2[pos][r][w] = sum;
    };

    // ---- prefetch pair-0 Q/mask ----
    int q0A = qc0 * 16, q0B = q0A + 16;
    const uint16_t* QA = qh + ((size_t)bh * 1024 + q0A) * 64;
    const uint16_t* QB_ = qh + ((size_t)bh * 1024 + q0B) * 64;
    bf8 aqA0 = *(const bf8*)&QA[(size_t)r * 64 + g * 8];
    bf8 aqA1 = *(const bf8*)&QA[(size_t)r * 64 + 32 + g * 8];
    bf8 aqB0 = *(const bf8*)&QB_[(size_t)r * 64 + g * 8];
    bf8 aqB1 = *(const bf8*)&QB_[(size_t)r * 64 + 32 + g * 8];
    uint32_t mbA = m2[((size_t)(b * 1024 + q0A + r) * 8 + w) * 4 + g];
    uint32_t mbB = m2[((size_t)(b * 1024 + q0B + r) * 8 + w) * 4 + g];

#pragma unroll 2
    for (int it = 0; it < 8; ++it) {
        const int pb = (it & 1) * 2;                 // P buffer pair for this iter
        q0A = (qc0 + 2 * it) * 16;
        q0B = q0A + 16;

        phase1(aqA0, aqA1, mbA, pb + 0, 0);
        phase1(aqB0, aqB1, mbB, pb + 1, 1);
        asm volatile("s_waitcnt lgkmcnt(0)" ::: "memory");
        __builtin_amdgcn_s_barrier();                            // BAR 1

        if (w < 2 && lane < 16) {
            float4 a = *(const float4*)&reds2[w][r][0];
            float4 c = *(const float4*)&reds2[w][r][4];
            invL2[w][r] = 1.f / (((a.x + a.y) + (a.z + a.w)) + ((c.x + c.y) + (c.z + c.w)));
        }

        // PV double: V in registers (vf), P from LDS -- no global loads here
        f32x4 oA = {}, oB = {};
        {
            const char* PrdA = (const char*)&P2[pb + 0][r][0] + khf * 1024 + g * 16;
            const char* PrdB = (const char*)&P2[pb + 1][r][0] + khf * 1024 + g * 16;
#pragma unroll
            for (int tt = 0; tt < 16; ++tt) {
                bf8 apA = *(const bf8*)(PrdA + tt * 64);
                bf8 apB = *(const bf8*)(PrdB + tt * 64);
                oA = __builtin_amdgcn_mfma_f32_16x16x32_bf16(apA, vf[tt], oA, 0, 0, 0);
                oB = __builtin_amdgcn_mfma_f32_16x16x32_bf16(apB, vf[tt], oB, 0, 0, 0);
            }
        }
        if (khf == 1) {
#pragma unroll
            for (int i = 0; i < 4; ++i) {
                Opart2[0][g * 4 + i][dc * 16 + r] = oA[i];
                Opart2[1][g * 4 + i][dc * 16 + r] = oB[i];
            }
        }
        asm volatile("s_waitcnt lgkmcnt(0)" ::: "memory");
        __builtin_amdgcn_s_barrier();                            // BAR 2

        // ---- prefetch next pair's Q/mask BEFORE any stores (loads precede
        //      stores in issue order -> their waits never require store drain)
        if (it < 7) {
            int q1A = (qc0 + 2 * (it + 1)) * 16, q1B = q1A + 16;
            const uint16_t* QnA = qh + ((size_t)bh * 1024 + q1A) * 64;
            const uint16_t* QnB = qh + ((size_t)bh * 1024 + q1B) * 64;
            aqA0 = *(const bf8*)&QnA[(size_t)r * 64 + g * 8];
            aqA1 = *(const bf8*)&QnA[(size_t)r * 64 + 32 + g * 8];
            aqB0 = *(const bf8*)&QnB[(size_t)r * 64 + g * 8];
            aqB1 = *(const bf8*)&QnB[(size_t)r * 64 + 32 + g * 8];
            mbA = m2[((size_t)(b * 1024 + q1A + r) * 8 + w) * 4 + g];
            mbB = m2[((size_t)(b * 1024 + q1B + r) * 8 + w) * 4 + g];
        }

        // ctx writes (normalized), both tiles
        if (khf == 0) {
            int d = h * 64 + dc * 16 + r;
            f32x4 ivA = *(const f32x4*)&invL2[0][g * 4];
            f32x4 ivB = *(const f32x4*)&invL2[1][g * 4];
#pragma unroll
            for (int i = 0; i < 4; ++i) {
                int qrA = q0A + g * 4 + i;
                int qrB = q0B + g * 4 + i;
                float vA = (oA[i] + Opart2[0][g * 4 + i][dc * 16 + r]) * ivA[i];
                float vB = (oB[i] + Opart2[1][g * 4 + i][dc * 16 + r]) * ivB[i];
                ctx[(size_t)(b * 1024 + qrA) * 1024 + d] = f2bf(vA);
                ctx[(size_t)(b * 1024 + qrB) * 1024 + d] = f2bf(vB);
            }
        }

        // attn stores: both tiles, rows {2w,2w+1}, 1KB-coalesced NT stores.
        // NO trailing barrier: next iteration's phase1 writes the OTHER P pair,
        // and all cross-iteration LDS reads drain at the lgkmcnt before BAR 1.
#pragma unroll
        for (int X = 0; X < 2; ++X) {
            int q0X = X ? q0B : q0A;
            float* arow = attn_out + (((size_t)(h * 4 + b) * 1024) + q0X) * 1024;
#pragma unroll
            for (int rr = 0; rr < 2; ++rr) {
                int row = w * 2 + rr;
                float inv = invL2[X][row];
                const uint16_t* Pr = &P2[pb + X][row][0];
                float* ar = arow + (size_t)row * 1024;
#pragma unroll
                for (int jj = 0; jj < 4; ++jj) {
                    int kx = jj * 256 + lane * 4;
                    uint2 sv = *(const uint2*)&Pr[kx];
                    f32x4 ov;
                    ov[0] = bf2f(sv.x & 0xffffu) * inv;
                    ov[1] = bf2f(sv.x >> 16) * inv;
                    ov[2] = bf2f(sv.y & 0xffffu) * inv;
                    ov[3] = bf2f(sv.y >> 16) * inv;
                    __builtin_nontemporal_store(ov, (f32x4*)&ar[kx]);
                }
            }
        }
    }
}

// ---------------- residual + LayerNorm (bf16 FC input) --------------------------
__global__ __launch_bounds__(256) void fc_ln(
        const uint16_t* __restrict__ fcob, const float* __restrict__ resid,
        const float* __restrict__ g, const float* __restrict__ bb,
        float* __restrict__ y) {
    const int r = blockIdx.x, tid = threadIdx.x;
    const int lane = tid & 63, w = tid >> 6;
    __shared__ float red[8];
    ushort4 xv = ((const ushort4*)(fcob + (size_t)r * 1024))[tid];
    float4 rv = ((const float4*)(resid + (size_t)r * 1024))[tid];
    float x[4] = {bf2f(xv.x) + rv.x, bf2f(xv.y) + rv.y,
                  bf2f(xv.z) + rv.z, bf2f(xv.w) + rv.w};
    float s = x[0] + x[1] + x[2] + x[3];
    float s2 = x[0] * x[0] + x[1] * x[1] + x[2] * x[2] + x[3] * x[3];
#pragma unroll
    for (int off = 32; off; off >>= 1) { s += __shfl_xor(s, off); s2 += __shfl_xor(s2, off); }
    if (lane == 0) { red[w] = s; red[4 + w] = s2; }
    __syncthreads();
    s = red[0] + red[1] + red[2] + red[3];
    s2 = red[4] + red[5] + red[6] + red[7];
    float mu = s * (1.f / 1024.f);
    float var = s2 * (1.f / 1024.f) - mu * mu;
    float inv = rsqrtf(var + LN_EPS);
    float4 gv = ((const float4*)g)[tid];
    float4 bv = ((const float4*)bb)[tid];
    float4 ov;
    ov.x = (x[0] - mu) * inv * gv.x + bv.x;
    ov.y = (x[1] - mu) * inv * gv.y + bv.y;
    ov.z = (x[2] - mu) * inv * gv.z + bv.z;
    ov.w = (x[3] - mu) * inv * gv.w + bv.w;
    ((float4*)(y + (size_t)r * 1024))[tid] = ov;
}

extern "C" void kernel_launch(void* const* d_in, const int* in_sizes, int n_in,
                              void* d_out, int out_size, void* d_ws, size_t ws_size,
                              hipStream_t stream) {
    const float* q    = (const float*)d_in[0];
    const float* k    = (const float*)d_in[1];
    const float* v    = (const float*)d_in[2];
    const int*   mask = (const int*)d_in[3];
    const float* wq_w = (const float*)d_in[4];
    const float* wq_b = (const float*)d_in[5];
    const float* wk_w = (const float*)d_in[6];
    const float* wk_b = (const float*)d_in[7];
    const float* wv_w = (const float*)d_in[8];
    const float* wv_b = (const float*)d_in[9];
    const float* fc_w = (const float*)d_in[10];
    const float* fc_b = (const float*)d_in[11];
    const float* ln_g = (const float*)d_in[12];
    const float* ln_b = (const float*)d_in[13];

    char* ws = (char*)d_ws;
    uint16_t* qb  = (uint16_t*)(ws);                    // 8 MB bf16 q
    uint16_t* kb  = (uint16_t*)(ws + (8u << 20));
    uint16_t* vb  = (uint16_t*)(ws + (16u << 20));
    uint16_t* wqb = (uint16_t*)(ws + (24u << 20));      // 2 MB each
    uint16_t* wkb = (uint16_t*)(ws + (26u << 20));
    uint16_t* wvb = (uint16_t*)(ws + (28u << 20));
    uint16_t* wfb = (uint16_t*)(ws + (30u << 20));
    uint16_t* qhb = (uint16_t*)(ws + (32u << 20));      // [bh][l][64]
    uint16_t* khb = (uint16_t*)(ws + (40u << 20));
    uint16_t* vtb = (uint16_t*)(ws + (48u << 20));      // [bh][d][l]
    uint16_t* ctx = (uint16_t*)(ws + (56u << 20));      // [b*l][1024]
    uint16_t* fcb = (uint16_t*)(ws + (64u << 20));      // 8 MB bf16 FC out
    uint32_t* m2  = (uint32_t*)(ws + (80u << 20));      // 512 KB mask bits

    float* y_out = (float*)d_out;
    float* attn_out = y_out + (size_t)4 * 1024 * 1024;

    prep<<<1536, 256, 0, stream>>>(q, k, v, wq_w, wk_w, wv_w, fc_w, mask,
                                   qb, kb, vb, wqb, wkb, wvb, wfb, m2);

    GArgs3 qkv;
    qkv.g[0] = {qb, wqb, wq_b, qhb, 0, 0.125f};
    qkv.g[1] = {kb, wkb, wk_b, khb, 0, 1.0f};
    qkv.g[2] = {vb, wvb, wv_b, vtb, 2, 1.0f};
    gemm_bt<<<dim3(8, 32, 3), 256, 0, stream>>>(qkv, 1024);

    attn_fused<<<256, 512, 0, stream>>>(qhb, khb, vtb, m2, attn_out, ctx);

    GArgs3 fc;
    fc.g[0] = {ctx, wfb, fc_b, fcb, 4, 1.0f};
    fc.g[1] = fc.g[0]; fc.g[2] = fc.g[0];
    gemm_bt<<<dim3(8, 32, 1), 256, 0, stream>>>(fc, 1024);

    fc_ln<<<4096, 256, 0, stream>>>(fcb, q, ln_g, ln_b, y_out);
}